// Round 2
// baseline (348.698 us; speedup 1.0000x reference)
//
#include <hip/hip_runtime.h>
#include <stdint.h>

// ---------------- constants ----------------
#define DIM   768
#define NTOK  196
#define TT    8
#define BB    16
#define MROWS 25088      // 3136 * 8
#define KD    768
#define HEADS 12

typedef __bf16 bf16x8 __attribute__((ext_vector_type(8)));
typedef float  f32x4  __attribute__((ext_vector_type(4)));
typedef unsigned short u16x4 __attribute__((ext_vector_type(4)));
typedef unsigned short u16x8 __attribute__((ext_vector_type(8)));

__device__ inline unsigned short f2bf(float f) {
  uint32_t u = __builtin_bit_cast(uint32_t, f);
  u += 0x7FFFu + ((u >> 16) & 1u);          // RNE
  return (unsigned short)(u >> 16);
}
__device__ inline float bf2f(unsigned short s) {
  uint32_t u = ((uint32_t)s) << 16;
  return __builtin_bit_cast(float, u);
}

// ---------------- weight fp32 -> bf16 convert ----------------
// layout in ws: [Wq (589824) | Wkv (1179648) | Wproj (589824)] elems
__global__ void wprep_kernel(const float* __restrict__ wq,
                             const float* __restrict__ wkv,
                             const float* __restrict__ wproj,
                             unsigned short* __restrict__ out) {
  int idx4 = blockIdx.x * blockDim.x + threadIdx.x;
  const int total4 = 2359296 / 4;
  if (idx4 >= total4) return;
  int e = idx4 * 4;
  const float* src; int off;
  if (e < 589824)        { src = wq;    off = e; }
  else if (e < 1769472)  { src = wkv;   off = e - 589824; }
  else                   { src = wproj; off = e - 1769472; }
  f32x4 v = *reinterpret_cast<const f32x4*>(&src[off]);
  u16x4 o;
  o[0] = f2bf(v[0]); o[1] = f2bf(v[1]); o[2] = f2bf(v[2]); o[3] = f2bf(v[3]);
  *reinterpret_cast<u16x4*>(&out[e]) = o;
}

// ---------------- CLS row copy (exact fp32) ----------------
__global__ void cls_kernel(const float* __restrict__ sx, float* __restrict__ out) {
  int i4 = blockIdx.x * blockDim.x + threadIdx.x;
  if (i4 < (128 * 768) / 4)
    reinterpret_cast<f32x4*>(out)[i4] = reinterpret_cast<const f32x4*>(sx)[i4];
}

// ---------------- GEMM: C[M,N] = A[M,K] * W[N,K]^T + bias ----------------
// MODE 0: A = gathered s_x + clip_time_pos (fp32->bf16), out = q_bf16, scale 0.125 in epilogue
// MODE 1: A = gathered t_x + vmae_time_pos (fp32->bf16), out = kv_bf16
// MODE 2: A = attn bf16 [M,K], out = d_out fp32 with permuted rows
template<int MODE>
__global__ __launch_bounds__(256)
void gemm_kernel(const float* __restrict__ srcA_f32,
                 const unsigned short* __restrict__ srcA_bf16,
                 const float* __restrict__ timepos,
                 const unsigned short* __restrict__ Wbf,
                 const float* __restrict__ bias,
                 void* __restrict__ outp,
                 int Ncols) {
  __shared__ unsigned short Alds[128 * 64];   // [row][k] bf16, 16 KB
  __shared__ unsigned short Blds[128 * 64];   // [ncol][k] bf16, 16 KB

  const int tid  = threadIdx.x;
  const int lane = tid & 63;
  const int w    = tid >> 6;
  const int wm   = w >> 1, wn = w & 1;
  const int m0   = blockIdx.y * 128;
  const int n0   = blockIdx.x * 128;

  f32x4 acc[4][4] = {};

  for (int kt = 0; kt < KD / 64; ++kt) {
    const int kbase = kt * 64;
    // ---- stage A (128 rows x 64 k) ----
    if (MODE < 2) {
      #pragma unroll
      for (int rep = 0; rep < 8; ++rep) {
        int flat = rep * 256 + tid;           // 0..2047 float4 chunks
        int r  = flat >> 4;                   // 0..127
        int c4 = (flat & 15) * 4;             // 0,4,...,60
        int m  = m0 + r;
        int bn = m >> 3, t = m & 7;
        int b  = bn / NTOK, n = bn - b * NTOK;
        long srow;
        if (MODE == 0) srow = (long)((1 + n) * 128 + b * 8 + t) * DIM;
        else           srow = (long)(b * (TT * NTOK) + t * NTOK + n) * DIM;
        f32x4 av = *reinterpret_cast<const f32x4*>(&srcA_f32[srow + kbase + c4]);
        f32x4 pv = *reinterpret_cast<const f32x4*>(&timepos[t * DIM + kbase + c4]);
        av += pv;
        u16x4 o;
        o[0] = f2bf(av[0]); o[1] = f2bf(av[1]); o[2] = f2bf(av[2]); o[3] = f2bf(av[3]);
        *reinterpret_cast<u16x4*>(&Alds[r * 64 + c4]) = o;
      }
    } else {
      #pragma unroll
      for (int rep = 0; rep < 4; ++rep) {
        int flat = rep * 256 + tid;           // 0..1023 chunks of 8
        int r  = flat >> 3;
        int c8 = (flat & 7) * 8;
        u16x8 sv = *reinterpret_cast<const u16x8*>(&srcA_bf16[(long)(m0 + r) * KD + kbase + c8]);
        *reinterpret_cast<u16x8*>(&Alds[r * 64 + c8]) = sv;
      }
    }
    // ---- stage B (128 ncols x 64 k) from bf16 weights ----
    #pragma unroll
    for (int rep = 0; rep < 4; ++rep) {
      int flat = rep * 256 + tid;
      int r  = flat >> 3;
      int c8 = (flat & 7) * 8;
      u16x8 sv = *reinterpret_cast<const u16x8*>(&Wbf[(long)(n0 + r) * KD + kbase + c8]);
      *reinterpret_cast<u16x8*>(&Blds[r * 64 + c8]) = sv;
    }
    __syncthreads();

    #pragma unroll
    for (int k0 = 0; k0 < 64; k0 += 32) {
      bf16x8 af[4], bfv[4];
      #pragma unroll
      for (int mf = 0; mf < 4; ++mf)
        af[mf] = *reinterpret_cast<const bf16x8*>(
            &Alds[(wm * 64 + mf * 16 + (lane & 15)) * 64 + k0 + (lane >> 4) * 8]);
      #pragma unroll
      for (int nf = 0; nf < 4; ++nf)
        bfv[nf] = *reinterpret_cast<const bf16x8*>(
            &Blds[(wn * 64 + nf * 16 + (lane & 15)) * 64 + k0 + (lane >> 4) * 8]);
      #pragma unroll
      for (int mf = 0; mf < 4; ++mf)
        #pragma unroll
        for (int nf = 0; nf < 4; ++nf)
          acc[mf][nf] = __builtin_amdgcn_mfma_f32_16x16x32_bf16(af[mf], bfv[nf], acc[mf][nf], 0, 0, 0);
    }
    __syncthreads();
  }

  // ---- epilogue ----
  #pragma unroll
  for (int mf = 0; mf < 4; ++mf) {
    #pragma unroll
    for (int nf = 0; nf < 4; ++nf) {
      int col = n0 + wn * 64 + nf * 16 + (lane & 15);
      float bsv = bias[col];
      #pragma unroll
      for (int i = 0; i < 4; ++i) {
        int row = m0 + wm * 64 + mf * 16 + (lane >> 4) * 4 + i;
        float v = acc[mf][nf][i] + bsv;
        if (MODE == 0) v *= 0.125f;                      // attention scale, exact pow2
        if (MODE < 2) {
          ((unsigned short*)outp)[(long)row * Ncols + col] = f2bf(v);
        } else {
          int bn = row >> 3, t = row & 7;
          int b  = bn / NTOK, n = bn - b * NTOK;
          ((float*)outp)[(long)((1 + n) * 128 + b * 8 + t) * DIM + col] = v;
        }
      }
    }
  }
}

// ---------------- attention: per (bn,h), t=8, hd=64 ----------------
__global__ __launch_bounds__(256)
void attn_kernel(const unsigned short* __restrict__ qb,
                 const unsigned short* __restrict__ kvb,
                 unsigned short* __restrict__ ob) {
  __shared__ __align__(16) float lds[4][3][8][68];   // [wave][q/k/v][t][d], pad 68
  const int tid  = threadIdx.x;
  const int lane = tid & 63;
  const int w    = tid >> 6;
  const int wid  = blockIdx.x * 4 + w;
  const int bn   = wid / HEADS;
  const int h    = wid - bn * HEADS;

  const int t  = lane >> 3;
  const int d0 = (lane & 7) * 8;
  const long qoff = (long)(bn * 8 + t) * DIM + h * 64 + d0;
  const long koff = (long)(bn * 8 + t) * (2 * DIM) + h * 64 + d0;

  // load q/k/v tiles (8x64 bf16 each), convert, stage to LDS
  u16x8 q8 = *reinterpret_cast<const u16x8*>(&qb[qoff]);
  u16x8 k8 = *reinterpret_cast<const u16x8*>(&kvb[koff]);
  u16x8 v8 = *reinterpret_cast<const u16x8*>(&kvb[koff + DIM]);
  f32x4 qa, qc, ka, kc, va, vc;
  #pragma unroll
  for (int e = 0; e < 4; ++e) {
    qa[e] = bf2f(q8[e]); qc[e] = bf2f(q8[e + 4]);
    ka[e] = bf2f(k8[e]); kc[e] = bf2f(k8[e + 4]);
    va[e] = bf2f(v8[e]); vc[e] = bf2f(v8[e + 4]);
  }
  *reinterpret_cast<f32x4*>(&lds[w][0][t][d0])     = qa;
  *reinterpret_cast<f32x4*>(&lds[w][0][t][d0 + 4]) = qc;
  *reinterpret_cast<f32x4*>(&lds[w][1][t][d0])     = ka;
  *reinterpret_cast<f32x4*>(&lds[w][1][t][d0 + 4]) = kc;
  *reinterpret_cast<f32x4*>(&lds[w][2][t][d0])     = va;
  *reinterpret_cast<f32x4*>(&lds[w][2][t][d0 + 4]) = vc;
  __syncthreads();

  // scores: lane owns (i,j) = (lane>>3, lane&7); q already scaled in GEMM epilogue
  const int i = lane >> 3, j = lane & 7;
  const f32x4* qi = reinterpret_cast<const f32x4*>(&lds[w][0][i][0]);
  const f32x4* kj = reinterpret_cast<const f32x4*>(&lds[w][1][j][0]);
  float s = 0.f;
  #pragma unroll
  for (int c = 0; c < 16; ++c) {
    f32x4 a = qi[c], b = kj[c];
    s += a[0] * b[0] + a[1] * b[1] + a[2] * b[2] + a[3] * b[3];
  }
  // softmax over j within each 8-lane group
  float m = s;
  m = fmaxf(m, __shfl_xor(m, 1));
  m = fmaxf(m, __shfl_xor(m, 2));
  m = fmaxf(m, __shfl_xor(m, 4));
  float e = __expf(s - m);
  float sum = e;
  sum += __shfl_xor(sum, 1);
  sum += __shfl_xor(sum, 2);
  sum += __shfl_xor(sum, 4);
  float p = e / sum;

  // PV: lane computes o[i][d0..d0+8)
  float o[8] = {};
  #pragma unroll
  for (int jj = 0; jj < 8; ++jj) {
    float pj = __shfl(p, (lane & 56) | jj);
    const f32x4* vj = reinterpret_cast<const f32x4*>(&lds[w][2][jj][d0]);
    f32x4 v0 = vj[0], v1 = vj[1];
    o[0] += pj * v0[0]; o[1] += pj * v0[1]; o[2] += pj * v0[2]; o[3] += pj * v0[3];
    o[4] += pj * v1[0]; o[5] += pj * v1[1]; o[6] += pj * v1[2]; o[7] += pj * v1[3];
  }
  u16x8 os;
  #pragma unroll
  for (int e2 = 0; e2 < 8; ++e2) os[e2] = f2bf(o[e2]);
  *reinterpret_cast<u16x8*>(&ob[qoff]) = os;   // same (row: bn*8+i==t, col) layout as q
}

// ---------------- launch ----------------
extern "C" void kernel_launch(void* const* d_in, const int* in_sizes, int n_in,
                              void* d_out, int out_size, void* d_ws, size_t ws_size,
                              hipStream_t stream) {
  const float* s_x       = (const float*)d_in[0];
  const float* t_x       = (const float*)d_in[1];
  const float* clip_pos  = (const float*)d_in[2];
  const float* vmae_pos  = (const float*)d_in[3];
  const float* Wq        = (const float*)d_in[4];
  const float* q_bias    = (const float*)d_in[5];
  const float* Wkv       = (const float*)d_in[6];
  const float* kv_bias   = (const float*)d_in[7];
  const float* Wproj     = (const float*)d_in[8];
  const float* proj_bias = (const float*)d_in[9];
  float* out = (float*)d_out;

  // workspace layout (bytes):
  //   w_bf   : 4,718,592   (Wq | Wkv | Wproj as bf16)
  //   q_bf   : 38,535,168  [25088 x 768] bf16
  //   kv_bf  : 77,070,336  [25088 x 1536] bf16
  //   at_bf  : 38,535,168  [25088 x 768] bf16
  // total = 158,859,264
  char* ws = (char*)d_ws;
  unsigned short* w_bf  = (unsigned short*)ws;
  unsigned short* q_bf  = (unsigned short*)(ws + 4718592);
  unsigned short* kv_bf = (unsigned short*)(ws + 4718592 + 38535168);
  unsigned short* at_bf = (unsigned short*)(ws + 4718592 + 38535168 + 77070336);

  wprep_kernel<<<dim3((589824 + 255) / 256), dim3(256), 0, stream>>>(Wq, Wkv, Wproj, w_bf);
  cls_kernel<<<dim3(96), dim3(256), 0, stream>>>(s_x, out);
  gemm_kernel<0><<<dim3(6, 196), dim3(256), 0, stream>>>(
      s_x, (const unsigned short*)nullptr, clip_pos, w_bf, q_bias, (void*)q_bf, 768);
  gemm_kernel<1><<<dim3(12, 196), dim3(256), 0, stream>>>(
      t_x, (const unsigned short*)nullptr, vmae_pos, w_bf + 589824, kv_bias, (void*)kv_bf, 1536);
  attn_kernel<<<dim3(37632 / 4), dim3(256), 0, stream>>>(q_bf, kv_bf, at_bf);
  gemm_kernel<2><<<dim3(6, 196), dim3(256), 0, stream>>>(
      (const float*)nullptr, at_bf, (const float*)nullptr, w_bf + 1769472, proj_bias,
      (void*)out, 768);
}

// Round 3
// 299.719 us; speedup vs baseline: 1.1634x; 1.1634x over previous
//
#include <hip/hip_runtime.h>
#include <stdint.h>

// ---------------- constants ----------------
#define DIM   768
#define NTOK  196
#define TT    8
#define BB    16
#define MROWS 25088      // 3136 * 8
#define HEADS 12

typedef __bf16 bf16x8 __attribute__((ext_vector_type(8)));
typedef float  f32x4  __attribute__((ext_vector_type(4)));
typedef unsigned short u16x4 __attribute__((ext_vector_type(4)));
typedef unsigned short u16x8 __attribute__((ext_vector_type(8)));

typedef __attribute__((address_space(1))) const void GAS;
typedef __attribute__((address_space(3))) void LAS;

__device__ inline unsigned short f2bf(float f) {
  uint32_t u = __builtin_bit_cast(uint32_t, f);
  u += 0x7FFFu + ((u >> 16) & 1u);          // RNE
  return (unsigned short)(u >> 16);
}
__device__ inline float bf2f(unsigned short s) {
  uint32_t u = ((uint32_t)s) << 16;
  return __builtin_bit_cast(float, u);
}

// async global->LDS, 16B per lane. LDS dest = wave-uniform base + lane*16.
__device__ inline void gl_lds16(const unsigned short* g, unsigned short* l) {
  __builtin_amdgcn_global_load_lds((GAS*)g, (LAS*)l, 16, 0, 0);
}

// ---------------- weight fp32 -> bf16 convert ----------------
// ws layout: [Wq (589824) | Wkv (1179648) | Wproj (589824)] elems
__global__ void wprep_kernel(const float* __restrict__ wq,
                             const float* __restrict__ wkv,
                             const float* __restrict__ wproj,
                             unsigned short* __restrict__ out) {
  int idx4 = blockIdx.x * blockDim.x + threadIdx.x;
  const int total4 = 2359296 / 4;
  if (idx4 >= total4) return;
  int e = idx4 * 4;
  const float* src; int off;
  if (e < 589824)        { src = wq;    off = e; }
  else if (e < 1769472)  { src = wkv;   off = e - 589824; }
  else                   { src = wproj; off = e - 1769472; }
  f32x4 v = *reinterpret_cast<const f32x4*>(&src[off]);
  u16x4 o;
  o[0] = f2bf(v[0]); o[1] = f2bf(v[1]); o[2] = f2bf(v[2]); o[3] = f2bf(v[3]);
  *reinterpret_cast<u16x4*>(&out[e]) = o;
}

// ---------------- CLS row copy (exact fp32) ----------------
__global__ void cls_kernel(const float* __restrict__ sx, float* __restrict__ out) {
  int i4 = blockIdx.x * blockDim.x + threadIdx.x;
  if (i4 < (128 * 768) / 4)
    reinterpret_cast<f32x4*>(out)[i4] = reinterpret_cast<const f32x4*>(sx)[i4];
}

// ---------------- A prep: gather + time_pos + fp32->bf16, one pass ----------------
// MODE 0: s_x patches  -> rows m=(b*196+n)*8+t from s_x[(1+n)*128 + b*8+t]
// MODE 1: t_x          -> rows m from t_x row b*1568 + t*196 + n
template<int MODE>
__global__ __launch_bounds__(256)
void aprep_kernel(const float* __restrict__ src, const float* __restrict__ timepos,
                  unsigned short* __restrict__ dst) {
  int idx = blockIdx.x * blockDim.x + threadIdx.x;      // one per 8 elems
  const int total = MROWS * (DIM / 8);
  if (idx >= total) return;
  int m  = idx / 96;
  int c8 = (idx - m * 96) * 8;
  int bn = m >> 3, t = m & 7;
  int b  = bn / NTOK, n = bn - b * NTOK;
  int srow = (MODE == 0) ? ((1 + n) * 128 + b * 8 + t)
                         : (b * (TT * NTOK) + t * NTOK + n);
  const float* sp = &src[srow * DIM + c8];
  const float* pp = &timepos[t * DIM + c8];
  f32x4 a0 = reinterpret_cast<const f32x4*>(sp)[0];
  f32x4 a1 = reinterpret_cast<const f32x4*>(sp)[1];
  f32x4 p0 = reinterpret_cast<const f32x4*>(pp)[0];
  f32x4 p1 = reinterpret_cast<const f32x4*>(pp)[1];
  a0 += p0; a1 += p1;
  u16x8 o;
  o[0] = f2bf(a0[0]); o[1] = f2bf(a0[1]); o[2] = f2bf(a0[2]); o[3] = f2bf(a0[3]);
  o[4] = f2bf(a1[0]); o[5] = f2bf(a1[1]); o[6] = f2bf(a1[2]); o[7] = f2bf(a1[3]);
  *reinterpret_cast<u16x8*>(&dst[m * DIM + c8]) = o;
}

// ---------------- GEMM: C[M,N] = A[M,768] * W[N,768]^T + bias ----------------
// m97 structure: 128x128 tile, BK=64, 4 waves (2x2), global_load_lds w16 staging.
// OUTMODE 0: bf16 out, *0.125 (q)   OUTMODE 1: bf16 out (kv)
// OUTMODE 2: fp32 out with permuted rows (proj -> d_out)
template<int OUTMODE>
__global__ __launch_bounds__(256)
void gemm_bf16(const unsigned short* __restrict__ Ag,
               const unsigned short* __restrict__ Wg,
               const float* __restrict__ bias,
               void* __restrict__ outp, int Ncols) {
  __shared__ unsigned short Alds[128 * 64];   // [row][k] bf16, 16 KB
  __shared__ unsigned short Blds[128 * 64];

  const int tid  = threadIdx.x;
  const int lane = tid & 63;
  const int w    = tid >> 6;
  const int wm   = w >> 1, wn = w & 1;
  const int m0   = blockIdx.y * 128;
  const int n0   = blockIdx.x * 128;
  const int segr = lane >> 3;                 // row within 8-row segment
  const int segc = (lane & 7) * 8;            // col elems within row

  f32x4 acc[4][4] = {};

  for (int kt = 0; kt < DIM / 64; ++kt) {
    const int kb = kt * 64;
    // stage A and B tiles: 16 segments of 1 KB each; wave w owns segs {it*4+w}
    #pragma unroll
    for (int it = 0; it < 4; ++it) {
      int seg = it * 4 + w;
      int r   = seg * 8 + segr;
      gl_lds16(&Ag[(m0 + r) * DIM + kb + segc], &Alds[seg * 512]);
      gl_lds16(&Wg[(n0 + r) * DIM + kb + segc], &Blds[seg * 512]);
    }
    __syncthreads();   // drains vmcnt

    #pragma unroll
    for (int k0 = 0; k0 < 64; k0 += 32) {
      bf16x8 af[4], bfv[4];
      #pragma unroll
      for (int mf = 0; mf < 4; ++mf)
        af[mf] = *reinterpret_cast<const bf16x8*>(
            &Alds[(wm * 64 + mf * 16 + (lane & 15)) * 64 + k0 + (lane >> 4) * 8]);
      #pragma unroll
      for (int nf = 0; nf < 4; ++nf)
        bfv[nf] = *reinterpret_cast<const bf16x8*>(
            &Blds[(wn * 64 + nf * 16 + (lane & 15)) * 64 + k0 + (lane >> 4) * 8]);
      #pragma unroll
      for (int mf = 0; mf < 4; ++mf)
        #pragma unroll
        for (int nf = 0; nf < 4; ++nf)
          acc[mf][nf] = __builtin_amdgcn_mfma_f32_16x16x32_bf16(af[mf], bfv[nf], acc[mf][nf], 0, 0, 0);
    }
    __syncthreads();
  }

  // ---- epilogue ----
  #pragma unroll
  for (int mf = 0; mf < 4; ++mf) {
    #pragma unroll
    for (int nf = 0; nf < 4; ++nf) {
      int col = n0 + wn * 64 + nf * 16 + (lane & 15);
      float bsv = bias[col];
      #pragma unroll
      for (int i = 0; i < 4; ++i) {
        int row = m0 + wm * 64 + mf * 16 + (lane >> 4) * 4 + i;
        float v = acc[mf][nf][i] + bsv;
        if (OUTMODE == 0) v *= 0.125f;                   // attention scale (pow2, exact)
        if (OUTMODE < 2) {
          ((unsigned short*)outp)[row * Ncols + col] = f2bf(v);
        } else {
          int bn = row >> 3, t = row & 7;
          int b  = bn / NTOK, n = bn - b * NTOK;
          ((float*)outp)[((1 + n) * 128 + b * 8 + t) * DIM + col] = v;
        }
      }
    }
  }
}

// ---------------- attention: per (bn,h), t=8, hd=64 ----------------
__global__ __launch_bounds__(256)
void attn_kernel(const unsigned short* __restrict__ qb,
                 const unsigned short* __restrict__ kvb,
                 unsigned short* __restrict__ ob) {
  __shared__ __align__(16) float lds[4][3][8][68];   // [wave][q/k/v][t][d], pad 68
  const int tid  = threadIdx.x;
  const int lane = tid & 63;
  const int w    = tid >> 6;
  const int wid  = blockIdx.x * 4 + w;
  const int bn   = wid / HEADS;
  const int h    = wid - bn * HEADS;

  const int t  = lane >> 3;
  const int d0 = (lane & 7) * 8;
  const int qoff = (bn * 8 + t) * DIM + h * 64 + d0;
  const int koff = (bn * 8 + t) * (2 * DIM) + h * 64 + d0;

  u16x8 q8 = *reinterpret_cast<const u16x8*>(&qb[qoff]);
  u16x8 k8 = *reinterpret_cast<const u16x8*>(&kvb[koff]);
  u16x8 v8 = *reinterpret_cast<const u16x8*>(&kvb[koff + DIM]);
  f32x4 qa, qc, ka, kc, va, vc;
  #pragma unroll
  for (int e = 0; e < 4; ++e) {
    qa[e] = bf2f(q8[e]); qc[e] = bf2f(q8[e + 4]);
    ka[e] = bf2f(k8[e]); kc[e] = bf2f(k8[e + 4]);
    va[e] = bf2f(v8[e]); vc[e] = bf2f(v8[e + 4]);
  }
  *reinterpret_cast<f32x4*>(&lds[w][0][t][d0])     = qa;
  *reinterpret_cast<f32x4*>(&lds[w][0][t][d0 + 4]) = qc;
  *reinterpret_cast<f32x4*>(&lds[w][1][t][d0])     = ka;
  *reinterpret_cast<f32x4*>(&lds[w][1][t][d0 + 4]) = kc;
  *reinterpret_cast<f32x4*>(&lds[w][2][t][d0])     = va;
  *reinterpret_cast<f32x4*>(&lds[w][2][t][d0 + 4]) = vc;
  __syncthreads();

  const int i = lane >> 3, j = lane & 7;
  const f32x4* qi = reinterpret_cast<const f32x4*>(&lds[w][0][i][0]);
  const f32x4* kj = reinterpret_cast<const f32x4*>(&lds[w][1][j][0]);
  float s = 0.f;
  #pragma unroll
  for (int c = 0; c < 16; ++c) {
    f32x4 a = qi[c], b = kj[c];
    s += a[0] * b[0] + a[1] * b[1] + a[2] * b[2] + a[3] * b[3];
  }
  float m = s;
  m = fmaxf(m, __shfl_xor(m, 1));
  m = fmaxf(m, __shfl_xor(m, 2));
  m = fmaxf(m, __shfl_xor(m, 4));
  float e = __expf(s - m);
  float sum = e;
  sum += __shfl_xor(sum, 1);
  sum += __shfl_xor(sum, 2);
  sum += __shfl_xor(sum, 4);
  float p = e / sum;

  float o[8] = {};
  #pragma unroll
  for (int jj = 0; jj < 8; ++jj) {
    float pj = __shfl(p, (lane & 56) | jj);
    const f32x4* vj = reinterpret_cast<const f32x4*>(&lds[w][2][jj][d0]);
    f32x4 v0 = vj[0], v1 = vj[1];
    o[0] += pj * v0[0]; o[1] += pj * v0[1]; o[2] += pj * v0[2]; o[3] += pj * v0[3];
    o[4] += pj * v1[0]; o[5] += pj * v1[1]; o[6] += pj * v1[2]; o[7] += pj * v1[3];
  }
  u16x8 os;
  #pragma unroll
  for (int e2 = 0; e2 < 8; ++e2) os[e2] = f2bf(o[e2]);
  *reinterpret_cast<u16x8*>(&ob[qoff]) = os;
}

// ---------------- launch ----------------
extern "C" void kernel_launch(void* const* d_in, const int* in_sizes, int n_in,
                              void* d_out, int out_size, void* d_ws, size_t ws_size,
                              hipStream_t stream) {
  const float* s_x       = (const float*)d_in[0];
  const float* t_x       = (const float*)d_in[1];
  const float* clip_pos  = (const float*)d_in[2];
  const float* vmae_pos  = (const float*)d_in[3];
  const float* Wq        = (const float*)d_in[4];
  const float* q_bias    = (const float*)d_in[5];
  const float* Wkv       = (const float*)d_in[6];
  const float* kv_bias   = (const float*)d_in[7];
  const float* Wproj     = (const float*)d_in[8];
  const float* proj_bias = (const float*)d_in[9];
  float* out = (float*)d_out;

  // workspace (bytes): w_bf 4,718,592 | buf1 38,535,168 (aq -> akv -> attn-out)
  //                    q_bf 38,535,168 | kv_bf 77,070,336   == 158,859,264 total
  char* ws = (char*)d_ws;
  unsigned short* w_bf  = (unsigned short*)ws;
  unsigned short* buf1  = (unsigned short*)(ws + 4718592);
  unsigned short* q_bf  = (unsigned short*)(ws + 4718592 + 38535168);
  unsigned short* kv_bf = (unsigned short*)(ws + 4718592 + 2 * 38535168);

  const int prep_blocks = (MROWS * 96 + 255) / 256;   // 9408

  wprep_kernel<<<dim3((589824 + 255) / 256), dim3(256), 0, stream>>>(Wq, Wkv, Wproj, w_bf);
  cls_kernel<<<dim3(96), dim3(256), 0, stream>>>(s_x, out);

  // Q path: prep A, GEMM -> q_bf
  aprep_kernel<0><<<dim3(prep_blocks), dim3(256), 0, stream>>>(s_x, clip_pos, buf1);
  gemm_bf16<0><<<dim3(6, 196), dim3(256), 0, stream>>>(buf1, w_bf, q_bias, (void*)q_bf, 768);

  // KV path: prep A (reuse buf1), GEMM -> kv_bf
  aprep_kernel<1><<<dim3(prep_blocks), dim3(256), 0, stream>>>(t_x, vmae_pos, buf1);
  gemm_bf16<1><<<dim3(12, 196), dim3(256), 0, stream>>>(buf1, w_bf + 589824, kv_bias, (void*)kv_bf, 1536);

  // attention -> buf1 (akv dead)
  attn_kernel<<<dim3(37632 / 4), dim3(256), 0, stream>>>(q_bf, kv_bf, buf1);

  // proj -> d_out (permuted rows)
  gemm_bf16<2><<<dim3(6, 196), dim3(256), 0, stream>>>(buf1, w_bf + 1769472, proj_bias, (void*)out, 768);
}

// Round 4
// 212.410 us; speedup vs baseline: 1.6416x; 1.4110x over previous
//
#include <hip/hip_runtime.h>
#include <stdint.h>

// ---------------- constants ----------------
#define DIM   768
#define NTOK  196
#define TT    8
#define MROWS 25088      // 3136 * 8
#define HEADS 12
#define NKT   12         // 768 / 64 K-tiles

typedef __bf16 bf16x8 __attribute__((ext_vector_type(8)));
typedef float  f32x4  __attribute__((ext_vector_type(4)));
typedef unsigned short u16x4 __attribute__((ext_vector_type(4)));
typedef unsigned short u16x8 __attribute__((ext_vector_type(8)));

typedef __attribute__((address_space(1))) const void GAS;
typedef __attribute__((address_space(3))) void LAS;

__device__ inline unsigned short f2bf(float f) {
  uint32_t u = __builtin_bit_cast(uint32_t, f);
  u += 0x7FFFu + ((u >> 16) & 1u);          // RNE
  return (unsigned short)(u >> 16);
}
__device__ inline float bf2f(unsigned short s) {
  uint32_t u = ((uint32_t)s) << 16;
  return __builtin_bit_cast(float, u);
}
__device__ inline void gl_lds16(const unsigned short* g, unsigned short* l) {
  __builtin_amdgcn_global_load_lds((GAS*)g, (LAS*)l, 16, 0, 0);
}
// bijective XCD-aware block swizzle (m204 variant)
__device__ inline int xcd_swz(int orig, int nwg) {
  int xcd = orig & 7, loc = orig >> 3;
  int q = nwg >> 3, r = nwg & 7;
  int base = (xcd < r) ? xcd * (q + 1) : r * (q + 1) + (xcd - r) * q;
  return base + loc;
}

#define WAITV(n) asm volatile("s_waitcnt vmcnt(" #n ")" ::: "memory")

// ---------------- weight fp32 -> bf16 convert ----------------
__global__ void wprep_kernel(const float* __restrict__ wq,
                             const float* __restrict__ wkv,
                             const float* __restrict__ wproj,
                             unsigned short* __restrict__ out) {
  int idx4 = blockIdx.x * blockDim.x + threadIdx.x;
  const int total4 = 2359296 / 4;
  if (idx4 >= total4) return;
  int e = idx4 * 4;
  const float* src; int off;
  if (e < 589824)        { src = wq;    off = e; }
  else if (e < 1769472)  { src = wkv;   off = e - 589824; }
  else                   { src = wproj; off = e - 1769472; }
  f32x4 v = *reinterpret_cast<const f32x4*>(&src[off]);
  u16x4 o;
  o[0] = f2bf(v[0]); o[1] = f2bf(v[1]); o[2] = f2bf(v[2]); o[3] = f2bf(v[3]);
  *reinterpret_cast<u16x4*>(&out[e]) = o;
}

// ---------------- CLS row copy (exact fp32) ----------------
__global__ void cls_kernel(const float* __restrict__ sx, float* __restrict__ out) {
  int i4 = blockIdx.x * blockDim.x + threadIdx.x;
  if (i4 < (128 * 768) / 4)
    reinterpret_cast<f32x4*>(out)[i4] = reinterpret_cast<const f32x4*>(sx)[i4];
}

// ---------------- A prep: gather + time_pos + fp32->bf16 ----------------
template<int MODE>
__global__ __launch_bounds__(256)
void aprep_kernel(const float* __restrict__ src, const float* __restrict__ timepos,
                  unsigned short* __restrict__ dst) {
  int idx = blockIdx.x * blockDim.x + threadIdx.x;      // one per 8 elems
  const int total = MROWS * (DIM / 8);
  if (idx >= total) return;
  int m  = idx / 96;
  int c8 = (idx - m * 96) * 8;
  int bn = m >> 3, t = m & 7;
  int b  = bn / NTOK, n = bn - b * NTOK;
  int srow = (MODE == 0) ? ((1 + n) * 128 + b * 8 + t)
                         : (b * (TT * NTOK) + t * NTOK + n);
  const float* sp = &src[srow * DIM + c8];
  const float* pp = &timepos[t * DIM + c8];
  f32x4 a0 = reinterpret_cast<const f32x4*>(sp)[0];
  f32x4 a1 = reinterpret_cast<const f32x4*>(sp)[1];
  f32x4 p0 = reinterpret_cast<const f32x4*>(pp)[0];
  f32x4 p1 = reinterpret_cast<const f32x4*>(pp)[1];
  a0 += p0; a1 += p1;
  u16x8 o;
  o[0] = f2bf(a0[0]); o[1] = f2bf(a0[1]); o[2] = f2bf(a0[2]); o[3] = f2bf(a0[3]);
  o[4] = f2bf(a1[0]); o[5] = f2bf(a1[1]); o[6] = f2bf(a1[2]); o[7] = f2bf(a1[3]);
  *reinterpret_cast<u16x8*>(&dst[m * DIM + c8]) = o;
}

// ---------------- GEMM: ring-3 counted-vmcnt, swizzled LDS ----------------
// BM=256, BN=128, BK=64, 8 waves (2 row-halves x 4 col-quarters), per-wave 128x32.
// MODE 0: merged Q/KV space, bids [0,588)=Q (bf16 out, x0.125), [588,1764)=KV (bf16).
// MODE 1: proj: bf16 A x Wproj -> fp32 d_out with permuted rows.
template<int MODE>
__global__ __launch_bounds__(512)
void gemm8(const unsigned short* __restrict__ As,
           const unsigned short* __restrict__ At,
           const unsigned short* __restrict__ W0,
           const unsigned short* __restrict__ W1,
           const float* __restrict__ b0,
           const float* __restrict__ b1,
           unsigned short* __restrict__ out0,
           unsigned short* __restrict__ out1,
           float* __restrict__ fout,
           int bid0) {
  // per buffer: A 16384 elems (32KB) + B 8192 elems (16KB); ring of 3 = 144 KB
  __shared__ unsigned short SB[3 * 24576];

  const int tid  = threadIdx.x;
  const int lane = tid & 63;
  const int w    = tid >> 6;                 // 0..7
  const int wm   = w >> 2;                   // row half (128 rows)
  const int wn   = w & 3;                    // col quarter (32 cols)

  int bid = xcd_swz(blockIdx.x, gridDim.x) + bid0;

  const unsigned short *Ag, *Wg;
  const float* bias;
  unsigned short* ob = nullptr;
  int rt, ct, Ncols;
  float scale = 1.0f;
  if (MODE == 0) {
    if (bid < 588) { rt = bid / 6;  ct = bid % 6;  Ag = As; Wg = W0; bias = b0; ob = out0; Ncols = 768;  scale = 0.125f; }
    else { int b2 = bid - 588; rt = b2 / 12; ct = b2 % 12; Ag = At; Wg = W1; bias = b1; ob = out1; Ncols = 1536; }
  } else {
    rt = bid / 6; ct = bid % 6; Ag = As; Wg = W0; bias = b0; Ncols = 768;
  }
  const int m0 = rt * 256;
  const int n0 = ct * 128;

  // --- staging: linear LDS dest, pre-swizzled global source (involution) ---
  auto stageA = [&](int kt) {
    const int kb = kt * 64;
    unsigned short* dst = &SB[(kt % 3) * 24576];
    #pragma unroll
    for (int rnd = 0; rnd < 4; ++rnd) {
      int s    = rnd * 8 + w;                         // 0..31
      int srow = s * 8 + (lane >> 3);                 // 0..255
      int scol = ((lane & 7) * 8) ^ ((srow & 7) << 3);
      gl_lds16(&Ag[(size_t)(m0 + srow) * 768 + kb + scol], dst + s * 512);
    }
  };
  auto stageB = [&](int kt) {
    const int kb = kt * 64;
    unsigned short* dst = &SB[(kt % 3) * 24576 + 16384];
    #pragma unroll
    for (int rnd = 0; rnd < 2; ++rnd) {
      int s    = rnd * 8 + w;                         // 0..15
      int srow = s * 8 + (lane >> 3);                 // 0..127
      int scol = ((lane & 7) * 8) ^ ((srow & 7) << 3);
      gl_lds16(&Wg[(size_t)(n0 + srow) * 768 + kb + scol], dst + s * 512);
    }
  };

  f32x4 acc[8][2] = {};

  // prologue: K-tiles 0 and 1 in flight (12 loads/thread)
  stageA(0); stageB(0);
  stageA(1); stageB(1);

  for (int kt = 0; kt < NKT; ++kt) {
    __builtin_amdgcn_sched_barrier(0);
    if (kt < NKT - 1) { WAITV(6); } else { WAITV(0); }
    __builtin_amdgcn_s_barrier();
    asm volatile("" ::: "memory");

    const unsigned short* Ab = &SB[(kt % 3) * 24576];
    const unsigned short* Bb = Ab + 16384;
    const bool st = (kt + 2) < NKT;

    if (st) stageA(kt + 2);
    __builtin_amdgcn_sched_barrier(0);

    #pragma unroll
    for (int ks = 0; ks < 2; ++ks) {
      bf16x8 af[8], bfv[2];
      const int kc = ks * 32 + (lane >> 4) * 8;
      #pragma unroll
      for (int fm = 0; fm < 8; ++fm) {
        int r = wm * 128 + fm * 16 + (lane & 15);
        af[fm] = *reinterpret_cast<const bf16x8*>(&Ab[r * 64 + (kc ^ ((r & 7) << 3))]);
      }
      #pragma unroll
      for (int fn = 0; fn < 2; ++fn) {
        int r = wn * 32 + fn * 16 + (lane & 15);
        bfv[fn] = *reinterpret_cast<const bf16x8*>(&Bb[r * 64 + (kc ^ ((r & 7) << 3))]);
      }
      __builtin_amdgcn_s_setprio(1);
      #pragma unroll
      for (int fm = 0; fm < 8; ++fm)
        #pragma unroll
        for (int fn = 0; fn < 2; ++fn)
          acc[fm][fn] = __builtin_amdgcn_mfma_f32_16x16x32_bf16(af[fm], bfv[fn], acc[fm][fn], 0, 0, 0);
      __builtin_amdgcn_s_setprio(0);
      if (ks == 0 && st) stageB(kt + 2);
      __builtin_amdgcn_sched_barrier(0);
    }
  }

  // ---- epilogue ----
  #pragma unroll
  for (int fm = 0; fm < 8; ++fm) {
    #pragma unroll
    for (int fn = 0; fn < 2; ++fn) {
      int col = n0 + wn * 32 + fn * 16 + (lane & 15);
      float bsv = bias[col];
      #pragma unroll
      for (int i = 0; i < 4; ++i) {
        int row = m0 + wm * 128 + fm * 16 + (lane >> 4) * 4 + i;
        float v = acc[fm][fn][i] + bsv;
        if (MODE == 0) {
          v *= scale;
          ob[(size_t)row * Ncols + col] = f2bf(v);
        } else {
          int bn = row >> 3, t = row & 7;
          int b  = bn / NTOK, n = bn - b * NTOK;
          fout[((1 + n) * 128 + b * 8 + t) * DIM + col] = v;
        }
      }
    }
  }
}

// ---------------- attention: per (bn,h), t=8, hd=64 ----------------
__global__ __launch_bounds__(256)
void attn_kernel(const unsigned short* __restrict__ qb,
                 const unsigned short* __restrict__ kvb,
                 unsigned short* __restrict__ ob) {
  __shared__ __align__(16) float lds[4][3][8][68];
  const int tid  = threadIdx.x;
  const int lane = tid & 63;
  const int w    = tid >> 6;
  const int wid  = blockIdx.x * 4 + w;
  const int bn   = wid / HEADS;
  const int h    = wid - bn * HEADS;

  const int t  = lane >> 3;
  const int d0 = (lane & 7) * 8;
  const int qoff = (bn * 8 + t) * DIM + h * 64 + d0;
  const int koff = (bn * 8 + t) * (2 * DIM) + h * 64 + d0;

  u16x8 q8 = *reinterpret_cast<const u16x8*>(&qb[qoff]);
  u16x8 k8 = *reinterpret_cast<const u16x8*>(&kvb[koff]);
  u16x8 v8 = *reinterpret_cast<const u16x8*>(&kvb[koff + DIM]);
  f32x4 qa, qc, ka, kc, va, vc;
  #pragma unroll
  for (int e = 0; e < 4; ++e) {
    qa[e] = bf2f(q8[e]); qc[e] = bf2f(q8[e + 4]);
    ka[e] = bf2f(k8[e]); kc[e] = bf2f(k8[e + 4]);
    va[e] = bf2f(v8[e]); vc[e] = bf2f(v8[e + 4]);
  }
  *reinterpret_cast<f32x4*>(&lds[w][0][t][d0])     = qa;
  *reinterpret_cast<f32x4*>(&lds[w][0][t][d0 + 4]) = qc;
  *reinterpret_cast<f32x4*>(&lds[w][1][t][d0])     = ka;
  *reinterpret_cast<f32x4*>(&lds[w][1][t][d0 + 4]) = kc;
  *reinterpret_cast<f32x4*>(&lds[w][2][t][d0])     = va;
  *reinterpret_cast<f32x4*>(&lds[w][2][t][d0 + 4]) = vc;
  __syncthreads();

  const int i = lane >> 3, j = lane & 7;
  const f32x4* qi = reinterpret_cast<const f32x4*>(&lds[w][0][i][0]);
  const f32x4* kj = reinterpret_cast<const f32x4*>(&lds[w][1][j][0]);
  float s = 0.f;
  #pragma unroll
  for (int c = 0; c < 16; ++c) {
    f32x4 a = qi[c], b = kj[c];
    s += a[0] * b[0] + a[1] * b[1] + a[2] * b[2] + a[3] * b[3];
  }
  float m = s;
  m = fmaxf(m, __shfl_xor(m, 1));
  m = fmaxf(m, __shfl_xor(m, 2));
  m = fmaxf(m, __shfl_xor(m, 4));
  float e = __expf(s - m);
  float sum = e;
  sum += __shfl_xor(sum, 1);
  sum += __shfl_xor(sum, 2);
  sum += __shfl_xor(sum, 4);
  float p = e / sum;

  float o[8] = {};
  #pragma unroll
  for (int jj = 0; jj < 8; ++jj) {
    float pj = __shfl(p, (lane & 56) | jj);
    const f32x4* vj = reinterpret_cast<const f32x4*>(&lds[w][2][jj][d0]);
    f32x4 v0 = vj[0], v1 = vj[1];
    o[0] += pj * v0[0]; o[1] += pj * v0[1]; o[2] += pj * v0[2]; o[3] += pj * v0[3];
    o[4] += pj * v1[0]; o[5] += pj * v1[1]; o[6] += pj * v1[2]; o[7] += pj * v1[3];
  }
  u16x8 os;
  #pragma unroll
  for (int e2 = 0; e2 < 8; ++e2) os[e2] = f2bf(o[e2]);
  *reinterpret_cast<u16x8*>(&ob[qoff]) = os;
}

// ---------------- launch ----------------
extern "C" void kernel_launch(void* const* d_in, const int* in_sizes, int n_in,
                              void* d_out, int out_size, void* d_ws, size_t ws_size,
                              hipStream_t stream) {
  const float* s_x       = (const float*)d_in[0];
  const float* t_x       = (const float*)d_in[1];
  const float* clip_pos  = (const float*)d_in[2];
  const float* vmae_pos  = (const float*)d_in[3];
  const float* Wq        = (const float*)d_in[4];
  const float* q_bias    = (const float*)d_in[5];
  const float* Wkv       = (const float*)d_in[6];
  const float* kv_bias   = (const float*)d_in[7];
  const float* Wproj     = (const float*)d_in[8];
  const float* proj_bias = (const float*)d_in[9];
  float* out = (float*)d_out;

  char* ws = (char*)d_ws;
  unsigned short* w_bf = (unsigned short*)ws;                    // 4,718,592 B
  const size_t ABUF = 38535168, KVB = 77070336, WB = 4718592;
  const bool merged = ws_size >= (WB + 3 * ABUF + KVB);

  const unsigned short* wq_bf = w_bf;
  const unsigned short* wkv_bf = w_bf + 589824;
  const unsigned short* wpj_bf = w_bf + 1769472;

  const int prep_blocks = (MROWS * 96 + 255) / 256;   // 9408

  wprep_kernel<<<dim3((589824 + 255) / 256), dim3(256), 0, stream>>>(Wq, Wkv, Wproj, w_bf);
  cls_kernel<<<dim3(96), dim3(256), 0, stream>>>(s_x, out);

  if (merged) {
    unsigned short* As    = (unsigned short*)(ws + WB);
    unsigned short* At    = (unsigned short*)(ws + WB + ABUF);
    unsigned short* q_bf  = (unsigned short*)(ws + WB + 2 * ABUF);
    unsigned short* kv_bf = (unsigned short*)(ws + WB + 3 * ABUF);
    aprep_kernel<0><<<dim3(prep_blocks), dim3(256), 0, stream>>>(s_x, clip_pos, As);
    aprep_kernel<1><<<dim3(prep_blocks), dim3(256), 0, stream>>>(t_x, vmae_pos, At);
    gemm8<0><<<dim3(1764), dim3(512), 0, stream>>>(As, At, wq_bf, wkv_bf, q_bias, kv_bias,
                                                   q_bf, kv_bf, nullptr, 0);
    attn_kernel<<<dim3(9408), dim3(256), 0, stream>>>(q_bf, kv_bf, As);
    gemm8<1><<<dim3(588), dim3(512), 0, stream>>>(As, nullptr, wpj_bf, nullptr, proj_bias,
                                                  nullptr, nullptr, nullptr, out, 0);
  } else {
    unsigned short* buf1  = (unsigned short*)(ws + WB);
    unsigned short* q_bf  = (unsigned short*)(ws + WB + ABUF);
    unsigned short* kv_bf = (unsigned short*)(ws + WB + 2 * ABUF);
    aprep_kernel<0><<<dim3(prep_blocks), dim3(256), 0, stream>>>(s_x, clip_pos, buf1);
    gemm8<0><<<dim3(588), dim3(512), 0, stream>>>(buf1, buf1, wq_bf, wkv_bf, q_bias, kv_bias,
                                                  q_bf, kv_bf, nullptr, 0);
    aprep_kernel<1><<<dim3(prep_blocks), dim3(256), 0, stream>>>(t_x, vmae_pos, buf1);
    gemm8<0><<<dim3(1176), dim3(512), 0, stream>>>(buf1, buf1, wq_bf, wkv_bf, q_bias, kv_bias,
                                                   q_bf, kv_bf, nullptr, 588);
    attn_kernel<<<dim3(9408), dim3(256), 0, stream>>>(q_bf, kv_bf, buf1);
    gemm8<1><<<dim3(588), dim3(512), 0, stream>>>(buf1, nullptr, wpj_bf, nullptr, proj_bias,
                                                  nullptr, nullptr, nullptr, out, 0);
  }
}